// Round 1
// 283.882 us; speedup vs baseline: 1.0006x; 1.0006x over previous
//
#include <hip/hip_runtime.h>
#include <hip/hip_bf16.h>

// Problem constants
#define SEGS   8
#define DIM    768
#define NVIS   100
#define BATCH  64
#define LTOK   512
#define NCHK   8        // reduction chunks per sequence
#define TPC    64       // tokens per chunk (512/8)
#define KS     8        // GEMM K-split
#define KLEN   96       // 768 / KS

// ws layout (float element offsets). PGEM overlays the chunk-partial region:
// combine1 fully consumes PCAP/PTRC/PVIS/counts before gemm writes PGEM
// (stream-ordered), so the regions can alias. Total ~6.8M floats = 27 MB.
#define OFF_PCAP  0                                   // [B][NCHK][S][D] caption chunk partials
#define OFF_PTRC  (OFF_PCAP + BATCH*NCHK*SEGS*DIM)    // [B][NCHK][S][D] trace chunk partials
#define OFF_PVIS  (OFF_PTRC + BATCH*NCHK*SEGS*DIM)    // [B][2][D] vision sums (chunks 0,1 only)
#define OFF_PCCNT (OFF_PVIS + BATCH*2*DIM)            // [B][NCHK][S] int caption chunk counts
#define OFF_PTCNT (OFF_PCCNT + BATCH*NCHK*SEGS)       // [B][NCHK][S] int trace chunk counts
#define OFF_TMEAN (OFF_PTCNT + BATCH*NCHK*SEGS)       // [B][9][D] trace means + vision mean (row 8)
#define OFF_TCNT  (OFF_TMEAN + BATCH*9*DIM)           // [B][S] int summed trace counts
#define OFF_PGEM  0                                   // [KS][B][9][D] GEMM partials (overlay)

// Evidence log: inputs f32 (r1 NaN sig), output f32 (r2 shuffle sig).
// r4: 3.5M global atomics = 93us gemm -> plain-store partials.
// r5: reduce 112us @ 12.6% HBM / 11% VALU / 15% occ = latency-bound;
//     fix = 2x grid + 4-deep load batching -> 85us.
// r6: reduce 85us @ 18.5% HBM / 13.9% VALU / 26.7% occ — still latency-bound;
//     grid cap was 12 waves/CU (1024 blk x 3 waves). Fix: column-half split
//     (thread = float2, grid 2048 -> 24 waves/CU cap) + 8-deep token load
//     batching (8 dwordx2 in flight/wave). Partial-store bytes unchanged.

// ---------------------------------------------------------------------------
// Segment-sum reduction -> plain-store chunk partials.
// grid = 2048: [type(2)][batch(64)][chunk(8)][colhalf(2)], block = 192
// (thread = 2 cols, float2). Sorted-mask run trick: seg id is block-uniform
// per token, changes rarely. 8 tokens' loads issued before any mask logic.
// ---------------------------------------------------------------------------
__global__ __launch_bounds__(192) void reduce_kernel(
    const float* __restrict__ vt_feat,
    const int* __restrict__ vt_mask,
    const float* __restrict__ cap_feat,
    const int* __restrict__ cap_mask,
    float* __restrict__ ws)
{
    const int bid  = blockIdx.x;
    const int type = bid >> 10;         // 0 = caption, 1 = trace/vision
    const int b    = (bid >> 4) & 63;
    const int ck   = (bid >> 1) & 7;
    const int half = bid & 1;
    const int tid  = threadIdx.x;       // 0..191
    const int c0   = half * 384 + tid * 2;   // this thread's 2 columns

    __shared__ __align__(16) int msk[TPC];
    __shared__ int scnt[SEGS + 1];
    if (tid < SEGS + 1) scnt[tid] = 0;
    if (tid < TPC) {
        const int l = ck * TPC + tid;
        int m;
        if (type == 0) m = cap_mask[b * 513 + 1 + l];
        else           m = (l >= NVIS) ? vt_mask[b * 412 + (l - NVIS)] : 0;
        msk[tid] = m;
    }
    __syncthreads();
    if (half == 0 && tid < TPC) {       // counts only needed once per (type,b,ck)
        const int m = msk[tid]; if (m > 0) atomicAdd(&scnt[m], 1);
    }

    float acc[SEGS][2];
#pragma unroll
    for (int s = 0; s < SEGS; ++s) { acc[s][0] = 0.f; acc[s][1] = 0.f; }
    float vacc[2] = {0.f, 0.f};
    float tmp[2]  = {0.f, 0.f};
    int cur = 0;

    const float* __restrict__ feat = (type == 0) ? cap_feat : vt_feat;
    const size_t base = (size_t)b * LTOK * DIM + (size_t)c0;

    for (int j = 0; j < TPC; j += 8) {
        // Batch 8 independent global loads BEFORE any dependent mask logic.
        const float* p = feat + base + (size_t)(ck * TPC + j) * DIM;
        float2 v[8];
#pragma unroll
        for (int u = 0; u < 8; ++u)
            v[u] = *reinterpret_cast<const float2*>(p + (size_t)u * DIM);
        const int4 m4a = *reinterpret_cast<const int4*>(&msk[j]);
        const int4 m4b = *reinterpret_cast<const int4*>(&msk[j + 4]);
        const int mm[8] = {m4a.x, m4a.y, m4a.z, m4a.w,
                           m4b.x, m4b.y, m4b.z, m4b.w};
#pragma unroll
        for (int u = 0; u < 8; ++u) {
            const int l = ck * TPC + j + u;
            if (type == 1 && l < NVIS) {
                vacc[0] += v[u].x; vacc[1] += v[u].y;
            } else {
                const int m = __builtin_amdgcn_readfirstlane(mm[u]);
                if (m != cur) {
#pragma unroll
                    for (int s = 0; s < SEGS; ++s)
                        if (cur == s + 1) {
                            acc[s][0] += tmp[0]; acc[s][1] += tmp[1];
                        }
                    tmp[0] = 0.f; tmp[1] = 0.f;
                    cur = m;
                }
                tmp[0] += v[u].x; tmp[1] += v[u].y;
            }
        }
    }
#pragma unroll
    for (int s = 0; s < SEGS; ++s)
        if (cur == s + 1) {
            acc[s][0] += tmp[0]; acc[s][1] += tmp[1];
        }

    __syncthreads();   // counts complete

    // Plain stores: all SEGS slots written (zeros where seg absent).
    float* __restrict__ pbase = ws + (type == 0 ? OFF_PCAP : OFF_PTRC)
                              + ((size_t)(b * NCHK + ck) * SEGS) * DIM + c0;
#pragma unroll
    for (int s = 0; s < SEGS; ++s) {
        *reinterpret_cast<float2*>(pbase + s * DIM) =
            make_float2(acc[s][0], acc[s][1]);
    }
    if (half == 0) {
        int* __restrict__ cbase = (int*)(ws + (type == 0 ? OFF_PCCNT : OFF_PTCNT))
                                + (b * NCHK + ck) * SEGS;
        if (tid < SEGS) cbase[tid] = scnt[tid + 1];
    }
    if (type == 1 && ck < 2) {   // vision tokens l<100 live in chunks 0,1
        *reinterpret_cast<float2*>(ws + OFF_PVIS + (size_t)(b * 2 + ck) * DIM + c0) =
            make_float2(vacc[0], vacc[1]);
    }
}

// ---------------------------------------------------------------------------
// Combine 1: fold chunk partials. Writes caption OUTPUT directly, trace means
// (pre-divided) + vision mean into TMEAN, trace counts into TCNT.
// grid = 3264 x 256 over 835584 elements.
// ---------------------------------------------------------------------------
__global__ __launch_bounds__(256) void combine1_kernel(
    const float* __restrict__ ws_c, float* __restrict__ ws,
    float* __restrict__ out)
{
    const int i = blockIdx.x * 256 + threadIdx.x;
    const int CAPN = BATCH * SEGS * DIM;   // 393216
    if (i < CAPN) {
        const int b = i / (SEGS * DIM);
        const int r = i % (SEGS * DIM);
        const int s = r / DIM, d = r % DIM;
        float sum = 0.f; int c = 0;
#pragma unroll
        for (int ck = 0; ck < NCHK; ++ck) {
            sum += ws_c[OFF_PCAP + ((size_t)((b * NCHK + ck) * SEGS + s)) * DIM + d];
            c   += ((const int*)(ws_c + OFF_PCCNT))[(b * NCHK + ck) * SEGS + s];
        }
        out[i] = (c > 0) ? sum / (float)c : 0.f;
    } else if (i < 2 * CAPN) {
        const int j = i - CAPN;
        const int b = j / (SEGS * DIM);
        const int r = j % (SEGS * DIM);
        const int s = r / DIM, d = r % DIM;
        float sum = 0.f; int c = 0;
#pragma unroll
        for (int ck = 0; ck < NCHK; ++ck) {
            sum += ws_c[OFF_PTRC + ((size_t)((b * NCHK + ck) * SEGS + s)) * DIM + d];
            c   += ((const int*)(ws_c + OFF_PTCNT))[(b * NCHK + ck) * SEGS + s];
        }
        ws[OFF_TMEAN + ((size_t)(b * 9 + s)) * DIM + d] = (c > 0) ? sum / (float)c : 0.f;
        if (d == 0) ((int*)(ws + OFF_TCNT))[b * SEGS + s] = c;
    } else {
        const int j = i - 2 * CAPN;
        const int b = j / DIM, d = j % DIM;
        ws[OFF_TMEAN + ((size_t)(b * 9 + 8)) * DIM + d] =
            (ws_c[OFF_PVIS + (size_t)(b * 2 + 0) * DIM + d] +
             ws_c[OFF_PVIS + (size_t)(b * 2 + 1) * DIM + d]) * (1.0f / (float)NVIS);
    }
}

// ---------------------------------------------------------------------------
// vt merge GEMM: A = TMEAN[b] (9 x 768, already divided), rows 0-7 x Wtop,
// row 8 x Wbot. K split 8 ways; partials PLAIN-stored into PGEM overlay.
// grid = 512 (64 batches x 8 k-chunks), block = 192 (thread = 4 cols)
// ---------------------------------------------------------------------------
__global__ __launch_bounds__(192) void gemm_kernel(
    const float* __restrict__ W,
    const float* __restrict__ ws_c,
    float* __restrict__ ws)
{
    const int b   = blockIdx.x >> 3;
    const int kc  = blockIdx.x & 7;
    const int k0  = kc * KLEN;
    const int tid = threadIdx.x;

    __shared__ __align__(16) float As[9][KLEN];
    for (int i = tid; i < 9 * KLEN; i += 192) {
        const int r = i / KLEN, k = i % KLEN;
        As[r][k] = ws_c[OFF_TMEAN + ((size_t)(b * 9 + r)) * DIM + k0 + k];
    }
    __syncthreads();

    float acc[9][4];
#pragma unroll
    for (int r = 0; r < 9; ++r) { acc[r][0]=0.f; acc[r][1]=0.f; acc[r][2]=0.f; acc[r][3]=0.f; }

    const float* __restrict__ Wt = W + (size_t)k0 * DIM + tid * 4;
    const float* __restrict__ Wb = W + (size_t)(DIM + k0) * DIM + tid * 4;

    for (int k = 0; k < KLEN; k += 4) {
        float a[9][4];
#pragma unroll
        for (int r = 0; r < 9; ++r) {
            const float4 t = *reinterpret_cast<const float4*>(&As[r][k]);
            a[r][0] = t.x; a[r][1] = t.y; a[r][2] = t.z; a[r][3] = t.w;
        }
#pragma unroll
        for (int u = 0; u < 4; ++u) {
            const float4 wt4 = *reinterpret_cast<const float4*>(Wt + (size_t)(k + u) * DIM);
            const float4 wb4 = *reinterpret_cast<const float4*>(Wb + (size_t)(k + u) * DIM);
            const float wt[4] = {wt4.x, wt4.y, wt4.z, wt4.w};
            const float wb[4] = {wb4.x, wb4.y, wb4.z, wb4.w};
#pragma unroll
            for (int r = 0; r < SEGS; ++r) {
#pragma unroll
                for (int j = 0; j < 4; ++j) acc[r][j] += a[r][u] * wt[j];
            }
#pragma unroll
            for (int j = 0; j < 4; ++j) acc[8][j] += a[8][u] * wb[j];
        }
    }

    float* __restrict__ P = ws + OFF_PGEM + ((size_t)(kc * BATCH + b) * 9) * DIM;
#pragma unroll
    for (int r = 0; r < 9; ++r)
        reinterpret_cast<float4*>(P + r * DIM)[tid] =
            make_float4(acc[r][0], acc[r][1], acc[r][2], acc[r][3]);
}

// ---------------------------------------------------------------------------
// Combine 2: fold 8 GEMM K-partials (seg row + vision row) + bias, apply
// presence mask, write vt OUTPUT.  grid = 1536 x 256 over 393216 elements.
// ---------------------------------------------------------------------------
__global__ __launch_bounds__(256) void combine2_kernel(
    const float* __restrict__ bias,
    const float* __restrict__ ws_c,
    float* __restrict__ out)
{
    const int j = blockIdx.x * 256 + threadIdx.x;
    const int HALF = BATCH * SEGS * DIM;   // 393216
    const int b = j / (SEGS * DIM);
    const int r = j % (SEGS * DIM);
    const int s = r / DIM, d = r % DIM;    // DIM=768 not pow2: use / and %
    const int c = ((const int*)(ws_c + OFF_TCNT))[b * SEGS + s];
    float v = 0.f;
    if (c > 0) {
        float sum = bias[d];
#pragma unroll
        for (int kc = 0; kc < KS; ++kc) {
            const float* P = ws_c + OFF_PGEM + ((size_t)(kc * BATCH + b) * 9) * DIM;
            sum += P[s * DIM + d] + P[8 * DIM + d];
        }
        v = sum;
    }
    out[HALF + j] = v;
}

extern "C" void kernel_launch(void* const* d_in, const int* in_sizes, int n_in,
                              void* d_out, int out_size, void* d_ws, size_t ws_size,
                              hipStream_t stream) {
    const float* vt_feat  = (const float*)d_in[0];
    const int*   vt_mask  = (const int*)d_in[1];
    const float* cap_feat = (const float*)d_in[2];
    const int*   cap_mask = (const int*)d_in[3];
    const float* W        = (const float*)d_in[4];
    const float* bias     = (const float*)d_in[5];
    float* out = (float*)d_out;
    float* ws = (float*)d_ws;

    // No memset: every ws slot is plain-stored before it is read.
    reduce_kernel  <<<2048, 192, 0, stream>>>(vt_feat, vt_mask, cap_feat, cap_mask, ws);
    combine1_kernel<<<3264, 256, 0, stream>>>(ws, ws, out);
    gemm_kernel    <<<512, 192, 0, stream>>>(W, ws, ws);
    combine2_kernel<<<1536, 256, 0, stream>>>(bias, ws, out);
}